// Round 5
// baseline (358.332 us; speedup 1.0000x reference)
//
#include <hip/hip_runtime.h>
#include <hip/hip_cooperative_groups.h>
#include <stdint.h>

namespace cgrp = cooperative_groups;

#define TPB 256
#define ROWS_PB 512
#define KROWS 8
#define TC 256
#define CS 16
#define IDXMASK 0x1FFFu
#define HIMASK  0xFFFFE000u

typedef unsigned long long u64;
typedef unsigned int u32;

__device__ __forceinline__ float waveReduceSum(float v){
#pragma unroll
  for (int o = 32; o > 0; o >>= 1) v += __shfl_down(v, o, 64);
  return v;
}

__device__ __forceinline__ float blockReduceSum(float v, float* buf4){
  v = waveReduceSum(v);
  __syncthreads();
  if ((threadIdx.x & 63) == 0) buf4[threadIdx.x >> 6] = v;
  __syncthreads();
  return buf4[0] + buf4[1] + buf4[2] + buf4[3];
}

// One direction of chamfer/color min. Expanded d = rx + ry - 2<x,y>; ry/rc in
// LDS float4.w; row side pre-negated -> 3 FMA/pair. K=8 rows/thread halves LDS
// bytes/pair. s2f packs 13-bit col idx into the dist's low mantissa in-register
// (and_or + min3); exact u64 (dist<<32|idx) re-pack at epilogue (values >= 0
// after clamp, so uint order == float order for the atomicMin).
template<bool NEED_IDX>
__device__ __forceinline__ void pass_phase(
    const float* __restrict__ rows, const float* __restrict__ cols,
    u64* __restrict__ outPack, u32* __restrict__ outDist, u32* __restrict__ outCol,
    int N, int cpc, int b, int rb, int chunk,
    float4* ptsT, float4* colT, u64* mPack, u32* mCol)
{
  const int t = threadIdx.x;
  const int lane = t & 63;
  const int w = t >> 6;
  const int rowBase = rb * ROWS_PB;
  const int colBase = chunk * cpc;

  float ax[KROWS], ay[KROWS], az[KROWS], rx[KROWS];
  float cr[KROWS], cg_[KROWS], cb[KROWS], rc[KROWS];
  float bD[KROWS], bC[KROWS];
#pragma unroll
  for (int k = 0; k < KROWS; k++){
    const float* p = rows + ((size_t)b * N + (rowBase + lane + 64 * k)) * 6;
    float p0 = p[0], p1 = p[1], p2 = p[2], p3 = p[3], p4 = p[4], p5 = p[5];
    ax[k] = -2.f * p0; ay[k] = -2.f * p1; az[k] = -2.f * p2;
    rx[k] = fmaf(p0, p0, fmaf(p1, p1, p2 * p2));
    cr[k] = -2.f * p3; cg_[k] = -2.f * p4; cb[k] = -2.f * p5;
    rc[k] = fmaf(p3, p3, fmaf(p4, p4, p5 * p5));
    bD[k] = 3.4e38f; bC[k] = 3.4e38f;
  }
  // init merge buffers (visibility covered by first staging barrier)
  mPack[t] = ~0ull; mPack[t + TPB] = ~0ull;
  mCol[t] = 0xFFFFFFFFu; mCol[t + TPB] = 0xFFFFFFFFu;

  for (int tb = 0; tb < cpc; tb += TC){
    const float* p = cols + ((size_t)b * N + (colBase + tb + t)) * 6;
    float q0 = p[0], q1 = p[1], q2 = p[2], q3 = p[3], q4 = p[4], q5 = p[5];
    ptsT[t] = make_float4(q0, q1, q2, fmaf(q0, q0, fmaf(q1, q1, q2 * q2)));
    colT[t] = make_float4(q3, q4, q5, fmaf(q3, q3, fmaf(q4, q4, q5 * q5)));
    __syncthreads();
#pragma unroll 4
    for (int j = 0; j < TC / 4; j += 2){
      const int mlA = j * 4 + w, mlB = mlA + 4;
      const float4 pA = ptsT[mlA], pB = ptsT[mlB];
      const float4 cA = colT[mlA], cB = colT[mlB];
      const u32 gA = (u32)(colBase + tb + mlA);
      const u32 gB = gA + 4;
#pragma unroll
      for (int k = 0; k < KROWS; k++){
        float tA = fmaf(ax[k], pA.x, fmaf(ay[k], pA.y, fmaf(az[k], pA.z, pA.w)));
        float tB = fmaf(ax[k], pB.x, fmaf(ay[k], pB.y, fmaf(az[k], pB.z, pB.w)));
        if (NEED_IDX){
          float pkA = __uint_as_float((__float_as_uint(tA) & HIMASK) | gA);
          float pkB = __uint_as_float((__float_as_uint(tB) & HIMASK) | gB);
          bD[k] = fminf(fminf(pkA, pkB), bD[k]);     // v_min3_f32
        } else {
          bD[k] = fminf(fminf(tA, tB), bD[k]);
        }
        float eA = fmaf(cr[k], cA.x, fmaf(cg_[k], cA.y, fmaf(cb[k], cA.z, cA.w)));
        float eB = fmaf(cr[k], cB.x, fmaf(cg_[k], cB.y, fmaf(cb[k], cB.z, cB.w)));
        bC[k] = fminf(fminf(eA, eB), bC[k]);
      }
    }
    __syncthreads();
  }

#pragma unroll
  for (int k = 0; k < KROWS; k++){
    int r = lane + 64 * k;
    u32 db = __float_as_uint(bD[k]);
    float dv; u32 idx = 0;
    if (NEED_IDX){ idx = db & IDXMASK; dv = __uint_as_float(db & HIMASK) + rx[k]; }
    else { dv = bD[k] + rx[k]; }
    dv = fmaxf(dv, 0.f);                              // clamp rounding < 0
    float cv = fmaxf(bC[k] + rc[k], 0.f);
    atomicMin(&mPack[r], ((u64)__float_as_uint(dv) << 32) | idx);
    atomicMin(&mCol[r], __float_as_uint(cv));
  }
  __syncthreads();
#pragma unroll
  for (int i = 0; i < ROWS_PB; i += TPB){
    int r = t + i;
    size_t g = (size_t)b * N + rowBase + r;
    u64 pk = mPack[r]; u32 cm = mCol[r];
    if (NEED_IDX) atomicMin(&outPack[g], pk);
    else          atomicMin(&outDist[g], (u32)(pk >> 32));
    atomicMin(&outCol[g], cm);
  }
}

// acc: [0]=edge_len, [1..6]=Sn[b][c], [7..12]=Se[b][c], [13]=cos, [14]=min sum,
//      [15]=completion counter (u32). mode: 0=cooperative (grid syncs),
//      1/2/3 = standalone phase launches (fallback path).
__global__ void __launch_bounds__(TPB, 4) combined(
    const float* __restrict__ gts, const float* __restrict__ preds,
    const float* __restrict__ normals, const int* __restrict__ edges,
    u64* __restrict__ packS2F, u32* __restrict__ distF2S,
    u32* __restrict__ colMin2, u32* __restrict__ colMin1,
    float* __restrict__ acc, float* __restrict__ out,
    int N, int E, int cpc, int nRowBlk, int nEdgeBlk, int mode)
{
  __shared__ float4 ptsT[TC];
  __shared__ float4 colT[TC];
  __shared__ u64 mPack[ROWS_PB];
  __shared__ u32 mCol[ROWS_PB];
  __shared__ float red4[4];
  __shared__ float buf7[7][4];
  __shared__ float chn[3];

  const int x = (int)blockIdx.x;
  const int t = threadIdx.x;

  if (mode <= 1){
    int perDB = (N / ROWS_PB) * CS;
    int dir = x / (2 * perDB);
    int rem = x - dir * 2 * perDB;
    int b = rem / perDB;
    int id = rem - b * perDB;
    int rb = id / CS;
    int chunk = id - rb * CS;
    if (dir == 0) pass_phase<true >(gts,  preds, packS2F, distF2S, colMin2,
                                    N, cpc, b, rb, chunk, ptsT, colT, mPack, mCol);
    else          pass_phase<false>(preds, gts,  packS2F, distF2S, colMin1,
                                    N, cpc, b, rb, chunk, ptsT, colT, mPack, mCol);
    if (mode == 1) return;
  }
  if (mode == 0) cgrp::this_grid().sync();

  if (mode == 0 || mode == 2){
    if (x < nRowBlk){
      int row = x * TPB + t;                       // BNtot == nRowBlk*TPB
      u64 pk = packS2F[row];
      float invN = 1.f / (float)N;
      float s = 3000.f * invN * __uint_as_float(distF2S[row])
              + 1650.f * invN * __uint_as_float((u32)(pk >> 32))
              + __uint_as_float(colMin1[row]) + __uint_as_float(colMin2[row]);
      s = blockReduceSum(s, red4);
      if (t == 0) atomicAdd(&acc[14], s);
    } else if (x < nRowBlk + nEdgeBlk){
      int gid = (x - nRowBlk) * TPB + t;
      int b = gid / E, e = gid - b * E;            // E%TPB==0 -> block-uniform b
      int e0 = edges[2 * e], e1 = edges[2 * e + 1];
      const float* p0 = preds + ((size_t)b * N + e0) * 6;
      const float* p1 = preds + ((size_t)b * N + e1) * 6;
      float ex = p0[0] - p1[0], ey = p0[1] - p1[1], ez = p0[2] - p1[2];
      u32 idx = (u32)packS2F[(size_t)b * N + e0];
      const float* nr = normals + ((size_t)b * N + idx) * 3;
      float n0 = nr[0], n1 = nr[1], n2 = nr[2];
      float t0 = truncf(ex), t1 = truncf(ey), t2 = truncf(ez);
      float v[7] = { fabsf(ex) + fabsf(ey) + fabsf(ez),
                     n0 * n0, n1 * n1, n2 * n2, t0 * t0, t1 * t1, t2 * t2 };
      int lane = t & 63, w = t >> 6;
#pragma unroll
      for (int q = 0; q < 7; q++){
        float s = waveReduceSum(v[q]);
        if (lane == 0) buf7[q][w] = s;
      }
      __syncthreads();
      if (t < 7){
        float s = buf7[t][0] + buf7[t][1] + buf7[t][2] + buf7[t][3];
        int off = (t == 0) ? 0 : ((t < 4) ? (1 + b * 3 + t - 1) : (7 + b * 3 + t - 4));
        atomicAdd(&acc[off], s);
      }
    }
    if (mode == 2) return;
  }
  if (mode == 0) cgrp::this_grid().sync();

  int xe = (mode == 3) ? x : x - nRowBlk;
  if (xe >= 0 && xe < nEdgeBlk){
    int gid = xe * TPB + t;
    int b = gid / E, e = gid - b * E;
    int e0 = edges[2 * e], e1 = edges[2 * e + 1];
    const float* p0 = preds + ((size_t)b * N + e0) * 6;
    const float* p1 = preds + ((size_t)b * N + e1) * 6;
    float ex = p0[0] - p1[0], ey = p0[1] - p1[1], ez = p0[2] - p1[2];
    u32 idx = (u32)packS2F[(size_t)b * N + e0];
    const float* nr = normals + ((size_t)b * N + idx) * 3;
    float t0 = truncf(ex), t1 = truncf(ey), t2 = truncf(ez);
    if (t == 0){
      // _unit_axis1 normalizes over the E axis: per (b,channel) norms
#pragma unroll
      for (int c = 0; c < 3; c++){
        float Sn = atomicAdd(&acc[1 + b * 3 + c], 0.f);
        float Se = atomicAdd(&acc[7 + b * 3 + c], 0.f);
        chn[c] = 1.f / (fmaxf(sqrtf(Sn), 1e-12f) * fmaxf(sqrtf(Se), 1e-12f));
      }
    }
    __syncthreads();
    float cosv = fabsf(nr[0] * t0 * chn[0] + nr[1] * t1 * chn[1] + nr[2] * t2 * chn[2]);
    float s = blockReduceSum(cosv, red4);
    if (t == 0){
      atomicAdd(&acc[13], s);
      __threadfence();
      u32 old = atomicAdd((u32*)&acc[15], 1u);
      if (old == (u32)(nEdgeBlk - 1)){
        float a0  = atomicAdd(&acc[0],  0.f);
        float a13 = atomicAdd(&acc[13], 0.f);
        float a14 = atomicAdd(&acc[14], 0.f);
        out[0] = a14 + a0 * (300.f / (float)E) + a13 * (0.5f / (float)E);
      }
    }
  }
}

extern "C" void kernel_launch(void* const* d_in, const int* in_sizes, int n_in,
                              void* d_out, int out_size, void* d_ws, size_t ws_size,
                              hipStream_t stream)
{
  const float* gts     = (const float*)d_in[0];
  const float* preds   = (const float*)d_in[1];
  const float* normals = (const float*)d_in[2];
  const int*   edges   = (const int*)d_in[3];

  const int B = 2;
  const int BNtot = in_sizes[2] / 3;   // B*N from gts_normals
  const int N = BNtot / B;
  const int E = in_sizes[3] / 2;

  char* ws = (char*)d_ws;
  u64* packS2F = (u64*)ws;                               // BN u64 (dist|idx)
  u32* distF2S = (u32*)(ws + (size_t)BNtot * 8);         // BN u32
  u32* colMin2 = (u32*)(ws + (size_t)BNtot * 12);        // BN u32
  u32* colMin1 = (u32*)(ws + (size_t)BNtot * 16);        // BN u32
  float* acc   = (float*)(ws + (size_t)BNtot * 20);      // 16 f32

  hipMemsetAsync(ws, 0xFF, (size_t)BNtot * 20, stream);  // +inf sentinels
  hipMemsetAsync(acc, 0, 64, stream);                    // sums + counter

  int cpc = N / CS;
  int nPass = 2 * B * (N / ROWS_PB) * CS;                // 1024 = 4 blocks/CU
  int nRowBlk = BNtot / TPB;                             // 64
  int nEdgeBlk = (B * E) / TPB;                          // 192
  float* outp = (float*)d_out;

  int mode0 = 0;
  void* args[] = { (void*)&gts, (void*)&preds, (void*)&normals, (void*)&edges,
                   (void*)&packS2F, (void*)&distF2S, (void*)&colMin2, (void*)&colMin1,
                   (void*)&acc, (void*)&outp, (void*)&N, (void*)&E, (void*)&cpc,
                   (void*)&nRowBlk, (void*)&nEdgeBlk, (void*)&mode0 };
  hipError_t err = hipLaunchCooperativeKernel((const void*)combined,
                                              dim3(nPass), dim3(TPB), args, 0, stream);
  if (err != hipSuccess){
    // fallback: same kernel as 3 plain launches (phase selector)
    combined<<<nPass, TPB, 0, stream>>>(gts, preds, normals, edges, packS2F, distF2S,
                                        colMin2, colMin1, acc, outp, N, E, cpc,
                                        nRowBlk, nEdgeBlk, 1);
    combined<<<nRowBlk + nEdgeBlk, TPB, 0, stream>>>(gts, preds, normals, edges, packS2F,
                                        distF2S, colMin2, colMin1, acc, outp, N, E, cpc,
                                        nRowBlk, nEdgeBlk, 2);
    combined<<<nEdgeBlk, TPB, 0, stream>>>(gts, preds, normals, edges, packS2F, distF2S,
                                        colMin2, colMin1, acc, outp, N, E, cpc,
                                        nRowBlk, nEdgeBlk, 3);
  }
}

// Round 7
// 131.868 us; speedup vs baseline: 2.7174x; 2.7174x over previous
//
#include <hip/hip_runtime.h>
#include <stdint.h>

#define TPB 256
#define ROWS_PB 512
#define KROWS 8
#define TC 256
#define CS 16

typedef unsigned long long u64;
typedef unsigned int u32;

__device__ __forceinline__ float waveReduceSum(float v){
#pragma unroll
  for (int o = 32; o > 0; o >>= 1) v += __shfl_down(v, o, 64);
  return v;
}

__device__ __forceinline__ u32 aload_u32(u32* p){
  return __hip_atomic_load(p, __ATOMIC_ACQUIRE, __HIP_MEMORY_SCOPE_AGENT);
}
__device__ __forceinline__ float aload_f32(float* p){
  return __hip_atomic_load(p, __ATOMIC_ACQUIRE, __HIP_MEMORY_SCOPE_AGENT);
}

// One direction of chamfer/color min. Expanded d = rx + ry - 2<x,y>; ry/rc in
// LDS float4.w; row side pre-negated -> 3 FMA/pair. KROWS=8 rows/thread halves
// LDS-pipe instrs/pair vs K=4 (the R2 bottleneck: 4x ds_read_b128 per 16
// pair-evals instead of per 8). All 4 waves cover the same 512 rows, each
// owning a column subset; cross-wave merge via LDS atomicMin, then one global
// atomicMin per row vs the 0xFF sentinel (uint order == float order, d>=0).
template<bool NEED_IDX>
__device__ __forceinline__ void pass_phase(
    const float* __restrict__ rows, const float* __restrict__ cols,
    u64* __restrict__ outPack, u32* __restrict__ outDist, u32* __restrict__ outCol,
    int N, int cpc, int b, int rb, int chunk,
    float4* ptsT, float4* colT, u64* mPack, u32* mCol)
{
  const int t = threadIdx.x, lane = t & 63, w = t >> 6;
  const int rowBase = rb * ROWS_PB, colBase = chunk * cpc;

  float ax[KROWS], ay[KROWS], az[KROWS], rx[KROWS];
  float cr[KROWS], cg_[KROWS], cb_[KROWS], rc[KROWS];
  float bD[KROWS], bC[KROWS];
  int bM[KROWS];
#pragma unroll
  for (int k = 0; k < KROWS; k++){
    const float* p = rows + ((size_t)b * N + (rowBase + lane + 64 * k)) * 6;
    float p0 = p[0], p1 = p[1], p2 = p[2], p3 = p[3], p4 = p[4], p5 = p[5];
    ax[k] = -2.f * p0; ay[k] = -2.f * p1; az[k] = -2.f * p2;
    rx[k] = fmaf(p0, p0, fmaf(p1, p1, p2 * p2));
    cr[k] = -2.f * p3; cg_[k] = -2.f * p4; cb_[k] = -2.f * p5;
    rc[k] = fmaf(p3, p3, fmaf(p4, p4, p5 * p5));
    bD[k] = 3.4e38f; bC[k] = 3.4e38f; bM[k] = 0;
  }
  // init LDS merge buffers; visibility covered by first staging barrier
  mPack[t] = ~0ull; mPack[t + TPB] = ~0ull;
  mCol[t] = ~0u;    mCol[t + TPB] = ~0u;

  for (int tb = 0; tb < cpc; tb += TC){
    const float* p = cols + ((size_t)b * N + (colBase + tb + t)) * 6;
    float q0 = p[0], q1 = p[1], q2 = p[2], q3 = p[3], q4 = p[4], q5 = p[5];
    ptsT[t] = make_float4(q0, q1, q2, fmaf(q0, q0, fmaf(q1, q1, q2 * q2)));
    colT[t] = make_float4(q3, q4, q5, fmaf(q3, q3, fmaf(q4, q4, q5 * q5)));
    __syncthreads();
#pragma unroll 2
    for (int j = 0; j < TC / 4; j += 2){
      const int mlA = j * 4 + w, mlB = mlA + 4;
      const float4 pA = ptsT[mlA], pB = ptsT[mlB];
      const float4 cA = colT[mlA], cB = colT[mlB];
      const int gA = colBase + tb + mlA;
      const int gB = gA + 4;
#pragma unroll
      for (int k = 0; k < KROWS; k++){
        float tA = fmaf(ax[k], pA.x, fmaf(ay[k], pA.y, fmaf(az[k], pA.z, pA.w)));
        float tB = fmaf(ax[k], pB.x, fmaf(ay[k], pB.y, fmaf(az[k], pB.z, pB.w)));
        if (NEED_IDX){
          if (tA < bD[k]) { bD[k] = tA; bM[k] = gA; }  // strict <, lower idx first
          if (tB < bD[k]) { bD[k] = tB; bM[k] = gB; }
        } else {
          bD[k] = fminf(fminf(tA, tB), bD[k]);
        }
        float eA = fmaf(cr[k], cA.x, fmaf(cg_[k], cA.y, fmaf(cb_[k], cA.z, cA.w)));
        float eB = fmaf(cr[k], cB.x, fmaf(cg_[k], cB.y, fmaf(cb_[k], cB.z, cB.w)));
        bC[k] = fminf(fminf(eA, eB), bC[k]);
      }
    }
    __syncthreads();
  }

#pragma unroll
  for (int k = 0; k < KROWS; k++){
    int r = lane + 64 * k;
    float dv = fmaxf(bD[k] + rx[k], 0.f);   // clamp: expanded form can round <0
    float cv = fmaxf(bC[k] + rc[k], 0.f);
    u64 pk = NEED_IDX ? (((u64)__float_as_uint(dv) << 32) | (u32)bM[k])
                      : ((u64)__float_as_uint(dv) << 32);
    atomicMin(&mPack[r], pk);               // ds atomics: distinct rows per lane
    atomicMin(&mCol[r], __float_as_uint(cv));
  }
  __syncthreads();
  for (int i = 0; i < ROWS_PB; i += TPB){
    int r = t + i;
    size_t g = (size_t)b * N + rowBase + r;
    if (NEED_IDX) atomicMin(&outPack[g], mPack[r]);
    else          atomicMin(&outDist[g], (u32)(mPack[r] >> 32));
    atomicMin(&outCol[g], mCol[r]);
  }
}

__global__ void __launch_bounds__(TPB) pass_kernel(
    const float* __restrict__ gts, const float* __restrict__ preds,
    u64* __restrict__ packS2F, u32* __restrict__ distF2S,
    u32* __restrict__ colMin2, u32* __restrict__ colMin1,
    int N, int cpc, int nPass)
{
  __shared__ __align__(16) char lds[14336];   // tiles 8K | mPack 4K | mCol 2K
  float4* ptsT = (float4*)lds;
  float4* colT = (float4*)(lds + 4096);
  u64* mPack   = (u64*)(lds + 8192);
  u32* mCol    = (u32*)(lds + 12288);

  const int x = (int)blockIdx.x;
  int perDB = nPass / 4;                      // blocks per (dir,b)
  int dir = x / (2 * perDB);
  int rem = x - dir * 2 * perDB;
  int b = rem / perDB;
  int id = rem - b * perDB;
  int rb = id / CS, chunk = id - rb * CS;
  if (dir == 0) pass_phase<true >(gts,  preds, packS2F, distF2S, colMin2,
                                  N, cpc, b, rb, chunk, ptsT, colT, mPack, mCol);
  else          pass_phase<false>(preds, gts,  packS2F, distF2S, colMin1,
                                  N, cpc, b, rb, chunk, ptsT, colT, mPack, mCol);
}

// acc: [0]=edge_len, [1..6]=Sn[b][c], [7..12]=Se[b][c], [13]=cos, [14]=min sum,
//      [15]=ctrEdge, [16]=ctrFin (u32, zeroed by memset).
// 256 blocks total -> guaranteed co-resident (<=1/CU), so the ctrEdge spin
// (edge blocks waiting on edge blocks) cannot deadlock. Pass results are
// visible via the kernel-launch boundary (no cross-kernel spin).
__global__ void __launch_bounds__(TPB) finish_kernel(
    const float* __restrict__ preds, const float* __restrict__ normals,
    const int* __restrict__ edges,
    u64* __restrict__ packS2F, u32* __restrict__ distF2S,
    u32* __restrict__ colMin2, u32* __restrict__ colMin1,
    float* __restrict__ acc, float* __restrict__ out,
    int N, int E, int nRowBlk, int nEdgeBlk)
{
  __shared__ float rbuf[4];
  __shared__ float buf7[7][4];
  __shared__ float chn[3];

  u32* ctrEdge = (u32*)(acc + 15);
  u32* ctrFin  = (u32*)(acc + 16);
  const int x = (int)blockIdx.x;
  const int t = threadIdx.x;
  const int nTot = nRowBlk + nEdgeBlk;

  if (x < nRowBlk){
    // weighted sum over the final min arrays
    int row = x * TPB + t;                    // BNtot == nRowBlk*TPB
    float invN = 1.f / (float)N;
    float s = 3000.f * invN * __uint_as_float(distF2S[row])
            + 1650.f * invN * __uint_as_float((u32)(packS2F[row] >> 32))
            + __uint_as_float(colMin1[row]) + __uint_as_float(colMin2[row]);
    s = waveReduceSum(s);
    if ((t & 63) == 0) rbuf[t >> 6] = s;
    __syncthreads();
    if (t == 0){
      atomicAdd(&acc[14], rbuf[0] + rbuf[1] + rbuf[2] + rbuf[3]);
      __threadfence();
      u32 old = atomicAdd(ctrFin, 1u);
      if (old == (u32)(nTot - 1)){
        float a0 = aload_f32(&acc[0]), a13 = aload_f32(&acc[13]), a14 = aload_f32(&acc[14]);
        out[0] = a14 + a0 * (300.f / (float)E) + a13 * (0.5f / (float)E);
      }
    }
    return;
  }

  // ---- edge blocks ----
  int gid = (x - nRowBlk) * TPB + t;
  int b = gid / E, e = gid - b * E;           // E%TPB==0 -> block-uniform b
  int e0 = edges[2 * e], e1 = edges[2 * e + 1];
  const float* p0 = preds + ((size_t)b * N + e0) * 6;
  const float* p1 = preds + ((size_t)b * N + e1) * 6;
  float ex = p0[0] - p1[0], ey = p0[1] - p1[1], ez = p0[2] - p1[2];
  u32 idx = (u32)packS2F[(size_t)b * N + e0];
  const float* nr = normals + ((size_t)b * N + idx) * 3;
  float n0 = nr[0], n1 = nr[1], n2 = nr[2];
  float t0 = truncf(ex), t1 = truncf(ey), t2 = truncf(ez);
  {
    float v[7] = { fabsf(ex) + fabsf(ey) + fabsf(ez),
                   n0 * n0, n1 * n1, n2 * n2, t0 * t0, t1 * t1, t2 * t2 };
    int lane = t & 63, w = t >> 6;
#pragma unroll
    for (int q = 0; q < 7; q++){
      float s = waveReduceSum(v[q]);
      if (lane == 0) buf7[q][w] = s;
    }
    __syncthreads();
    if (t < 7){
      float s = buf7[t][0] + buf7[t][1] + buf7[t][2] + buf7[t][3];
      int off = (t == 0) ? 0 : ((t < 4) ? (1 + b * 3 + t - 1) : (7 + b * 3 + t - 4));
      atomicAdd(&acc[off], s);
    }
    __syncthreads();
    if (t == 0){ __threadfence(); atomicAdd(ctrEdge, 1u); }
  }
  // wait for all (co-resident) edge blocks' Sn/Se sums
  if (t == 0){
    while (aload_u32(ctrEdge) < (u32)nEdgeBlk) __builtin_amdgcn_s_sleep(2);
    // _unit_axis1 normalizes over the E axis: per (b,channel) norms
#pragma unroll
    for (int c = 0; c < 3; c++){
      float Sn = aload_f32(&acc[1 + b * 3 + c]);
      float Se = aload_f32(&acc[7 + b * 3 + c]);
      chn[c] = 1.f / (fmaxf(sqrtf(Sn), 1e-12f) * fmaxf(sqrtf(Se), 1e-12f));
    }
  }
  __syncthreads();
  float cosv = fabsf(n0 * t0 * chn[0] + n1 * t1 * chn[1] + n2 * t2 * chn[2]);
  cosv = waveReduceSum(cosv);
  if ((t & 63) == 0) rbuf[t >> 6] = cosv;
  __syncthreads();
  if (t == 0){
    atomicAdd(&acc[13], rbuf[0] + rbuf[1] + rbuf[2] + rbuf[3]);
    __threadfence();
    u32 old = atomicAdd(ctrFin, 1u);
    if (old == (u32)(nTot - 1)){
      float a0 = aload_f32(&acc[0]), a13 = aload_f32(&acc[13]), a14 = aload_f32(&acc[14]);
      out[0] = a14 + a0 * (300.f / (float)E) + a13 * (0.5f / (float)E);
    }
  }
}

extern "C" void kernel_launch(void* const* d_in, const int* in_sizes, int n_in,
                              void* d_out, int out_size, void* d_ws, size_t ws_size,
                              hipStream_t stream)
{
  const float* gts     = (const float*)d_in[0];
  const float* preds   = (const float*)d_in[1];
  const float* normals = (const float*)d_in[2];
  const int*   edges   = (const int*)d_in[3];

  const int B = 2;
  const int BNtot = in_sizes[2] / 3;   // B*N from gts_normals
  const int N = BNtot / B;
  const int E = in_sizes[3] / 2;

  char* ws = (char*)d_ws;
  float* acc   = (float*)ws;                                  // 32 f32 (128 B)
  u64* packS2F = (u64*)(ws + 128);                            // BN u64 (dist|idx)
  u32* distF2S = (u32*)(ws + 128 + (size_t)BNtot * 8);        // BN u32
  u32* colMin2 = (u32*)(ws + 128 + (size_t)BNtot * 12);       // BN u32
  u32* colMin1 = (u32*)(ws + 128 + (size_t)BNtot * 16);       // BN u32

  hipMemsetAsync(ws, 0, 128, stream);                         // acc + counters
  hipMemsetAsync(ws + 128, 0xFF, (size_t)BNtot * 20, stream); // +inf sentinels

  int cpc = N / CS;                                    // 512
  int nPass = 2 * B * (N / ROWS_PB) * CS;              // 1024
  int nRowBlk = BNtot / TPB;                           // 64
  int nEdgeBlk = (B * E) / TPB;                        // 192

  pass_kernel<<<nPass, TPB, 0, stream>>>(gts, preds, packS2F, distF2S,
                                         colMin2, colMin1, N, cpc, nPass);
  finish_kernel<<<nRowBlk + nEdgeBlk, TPB, 0, stream>>>(
      preds, normals, edges, packS2F, distF2S, colMin2, colMin1,
      acc, (float*)d_out, N, E, nRowBlk, nEdgeBlk);
}